// Round 4
// baseline (541.479 us; speedup 1.0000x reference)
//
#include <hip/hip_runtime.h>

// Local context aggregation (DGCNN edge-conv style), MI355X.
// Pipeline:
//   k_feat : per-point transforms yF1=A1f·x, yFc=(A2f-A1f)·x, yD1, yDc + xx=|x|^2
//   k_prep : split-bf16 tables hl[n][hi96|lo96] + transposed xT[n][96] f32
//   k_dist : FUSED MFMA score + top-k. Per block: 32 query rows x all 4096 candidates.
//            Query rows ride the MFMA col axis -> each lane's scores cover only 2 rows
//            -> per-lane top-8 lists in registers. LDS merge -> fp32 top-24 -> exact
//            f64 re-rank -> idx[20]. Scores never touch HBM.
//   k_stats/k_bn/k_out : BN over edge norms + directional leaky act + mean over k
// ws usage: ~39 MB fixed.

namespace {
constexpr int BB = 4;
constexpr int NN = 4096;
constexpr int KK = 20;
constexpr int CC = 96;      // 32 features x 3 dims
constexpr int OO = 32;
constexpr int PTS = BB * NN;
constexpr int LTOP = 8;     // per-lane top list
constexpr int TCAND = 24;   // candidates sent to f64 refine
constexpr int RSTRIDE = 100;
}

using bf16x8 = __attribute__((ext_vector_type(8))) short;
using f32x4 = __attribute__((ext_vector_type(4))) float;

__device__ __forceinline__ unsigned short f2bf(float f) {
  unsigned u = __float_as_uint(f);
  return (unsigned short)((u + 0x7fff + ((u >> 16) & 1)) >> 16);
}
__device__ __forceinline__ float bf2f(unsigned short b) {
  return __uint_as_float((unsigned)b << 16);
}

// ---------------- kernel 1: per-point transforms + |x|^2 ----------------
__global__ __launch_bounds__(256) void k_feat(
    const float* __restrict__ x, const float* __restrict__ Wf,
    const float* __restrict__ Wd,
    float* __restrict__ yF1, float* __restrict__ yFc,
    float* __restrict__ yD1, float* __restrict__ yDc,
    float* __restrict__ xx) {
  __shared__ float sW[4][32][32];
  __shared__ float sx[8][RSTRIDE];
  const int t = threadIdx.x;
  for (int i = t; i < 2048; i += 256) {
    int o = i & 31, f = (i >> 5) & 31, which = i >> 10;
    const float* W = which ? Wd : Wf;
    float a1 = W[o * 64 + f], a2 = W[o * 64 + 32 + f];
    sW[which * 2 + 0][f][o] = a1;
    sW[which * 2 + 1][f][o] = a2 - a1;
  }
  const int b = blockIdx.x >> 9;
  const int n0 = (blockIdx.x & 511) * 8;
  for (int i = t; i < 8 * CC; i += 256) {
    int pl = i & 7, c = i >> 3;
    sx[pl][c] = x[((size_t)b * CC + c) * NN + n0 + pl];
  }
  __syncthreads();
  const int o = t & 31, pl = t >> 5;
  float aF1[3] = {0.f, 0.f, 0.f}, aFc[3] = {0.f, 0.f, 0.f};
  float aD1[3] = {0.f, 0.f, 0.f}, aDc[3] = {0.f, 0.f, 0.f};
#pragma unroll
  for (int f = 0; f < 32; ++f) {
    float w0 = sW[0][f][o], w1 = sW[1][f][o];
    float w2 = sW[2][f][o], w3 = sW[3][f][o];
#pragma unroll
    for (int dd = 0; dd < 3; ++dd) {
      float v = sx[pl][f * 3 + dd];
      aF1[dd] = fmaf(w0, v, aF1[dd]);
      aFc[dd] = fmaf(w1, v, aFc[dd]);
      aD1[dd] = fmaf(w2, v, aD1[dd]);
      aDc[dd] = fmaf(w3, v, aDc[dd]);
    }
  }
  const size_t pt = (size_t)(b * NN + n0 + pl) * CC + o * 3;
#pragma unroll
  for (int dd = 0; dd < 3; ++dd) {
    yF1[pt + dd] = aF1[dd]; yFc[pt + dd] = aFc[dd];
    yD1[pt + dd] = aD1[dd]; yDc[pt + dd] = aDc[dd];
  }
  float part = 0.f;
#pragma unroll
  for (int dd = 0; dd < 3; ++dd) { float v = sx[pl][o * 3 + dd]; part += v * v; }
#pragma unroll
  for (int off = 16; off >= 1; off >>= 1) part += __shfl_down(part, off, 32);
  if (o == 0) xx[b * NN + n0 + pl] = part;
}

// ---------------- kernel 1b: split-bf16 + transposed tables ----------------
__global__ __launch_bounds__(256) void k_prep(
    const float* __restrict__ x, unsigned short* __restrict__ hl,
    float* __restrict__ xT) {
  __shared__ float tile[CC][65];
  const int t = threadIdx.x;
  const int b = blockIdx.x >> 6;             // 64 blocks per batch
  const int n0 = (blockIdx.x & 63) * 64;
#pragma unroll
  for (int i = 0; i < 24; ++i) {
    int v = i * 256 + t;
    int c = v >> 6, nn = v & 63;
    tile[c][nn] = x[((size_t)b * CC + c) * NN + n0 + nn];
  }
  __syncthreads();
  // hl rows: [hi 96 | lo 96] bf16, written as 24 x 16B chunks per row
#pragma unroll
  for (int i = 0; i < 6; ++i) {
    int v = i * 256 + t;                    // 0..1535 over 64 rows x 24 chunks
    int row = v / 24, k8 = v % 24;
    unsigned hb[4];
    if (k8 < 12) {
      int c0 = k8 * 8;
#pragma unroll
      for (int j = 0; j < 4; ++j) {
        unsigned short l16 = f2bf(tile[c0 + 2 * j][row]);
        unsigned short h16 = f2bf(tile[c0 + 2 * j + 1][row]);
        hb[j] = (unsigned)l16 | ((unsigned)h16 << 16);
      }
    } else {
      int c0 = (k8 - 12) * 8;
#pragma unroll
      for (int j = 0; j < 4; ++j) {
        float f0 = tile[c0 + 2 * j][row], f1 = tile[c0 + 2 * j + 1][row];
        unsigned short h0 = f2bf(f0), h1 = f2bf(f1);
        unsigned short l0 = f2bf(f0 - bf2f(h0)), l1 = f2bf(f1 - bf2f(h1));
        hb[j] = (unsigned)l0 | ((unsigned)l1 << 16);
      }
    }
    *(uint4*)(hl + (size_t)(b * NN + n0 + row) * 192 + k8 * 8) =
        make_uint4(hb[0], hb[1], hb[2], hb[3]);
  }
  // xT rows: 96 f32 contiguous per point
#pragma unroll
  for (int i = 0; i < 6; ++i) {
    int v = i * 256 + t;
    int row = v / 24, q = v % 24;
    float4 o4;
    o4.x = tile[q * 4 + 0][row]; o4.y = tile[q * 4 + 1][row];
    o4.z = tile[q * 4 + 2][row]; o4.w = tile[q * 4 + 3][row];
    *(float4*)(xT + (size_t)(b * NN + n0 + row) * CC + q * 4) = o4;
  }
}

// ---------------- kernel 2: FUSED MFMA score + top-k ----------------
// Block = 256 thr = 4 waves. 32 query rows (nbase..nbase+31), all 4096 candidates,
// m split 4 ways across waves (1024 each). Query fragments register-resident.
// Score = dot - 0.5*xx[m] (monotone in true dist); selection refined in f64.
__global__ __launch_bounds__(256) void k_dist(
    const unsigned short* __restrict__ hl, const float* __restrict__ xx,
    const float* __restrict__ xT, int* __restrict__ idxout) {
  __shared__ float sSc[32][4][4][LTOP];
  __shared__ int sId[32][4][4][LTOP];
  const int t = threadIdx.x, lane = t & 63, w = t >> 6;
  const int b = blockIdx.y;
  const int nbase = blockIdx.x * 32;
  const unsigned short* hb = hl + (size_t)b * NN * 192;
  const float* xxb = xx + b * NN;
  const int kl = lane >> 4, pr = lane & 15;

  // resident operand-B fragments: the block's 32 query rows (col axis)
  bf16x8 rHf[2][3], rLf[2][3];
#pragma unroll
  for (int ns = 0; ns < 2; ++ns)
#pragma unroll
    for (int kb = 0; kb < 3; ++kb) {
      const unsigned short* p = hb + (size_t)(nbase + ns * 16 + pr) * 192 + (kb * 4 + kl) * 8;
      rHf[ns][kb] = *(const bf16x8*)p;
      rLf[ns][kb] = *(const bf16x8*)(p + 96);
    }

  float ls[2][LTOP]; int lid[2][LTOP];
#pragma unroll
  for (int ns = 0; ns < 2; ++ns)
#pragma unroll
    for (int j = 0; j < LTOP; ++j) { ls[ns][j] = -3.0e38f; lid[ns][j] = 0x7fffffff; }

  for (int mt = 0; mt < 16; ++mt) {
    const int mbase = w * 1024 + mt * 64;
    f32x4 acc[2][4];
#pragma unroll
    for (int ca = 0; ca < 4; ++ca) {
      float4 xv = *(const float4*)&xxb[mbase + ca * 16 + kl * 4];
      f32x4 ini = {-0.5f * xv.x, -0.5f * xv.y, -0.5f * xv.z, -0.5f * xv.w};
      acc[0][ca] = ini; acc[1][ca] = ini;
    }
#pragma unroll
    for (int kb = 0; kb < 3; ++kb) {
      bf16x8 aH[4], aL[4];
#pragma unroll
      for (int ca = 0; ca < 4; ++ca) {
        const unsigned short* p = hb + (size_t)(mbase + ca * 16 + pr) * 192 + (kb * 4 + kl) * 8;
        aH[ca] = *(const bf16x8*)p;
        aL[ca] = *(const bf16x8*)(p + 96);
      }
      // (candH+candL)·(rowH+rowL) ~= cH·rH + cL·rH + cH·rL  (lo·lo ~2^-16)
#pragma unroll
      for (int ns = 0; ns < 2; ++ns)
#pragma unroll
        for (int ca = 0; ca < 4; ++ca) {
          acc[ns][ca] = __builtin_amdgcn_mfma_f32_16x16x32_bf16(aH[ca], rHf[ns][kb], acc[ns][ca], 0, 0, 0);
          acc[ns][ca] = __builtin_amdgcn_mfma_f32_16x16x32_bf16(aL[ca], rHf[ns][kb], acc[ns][ca], 0, 0, 0);
          acc[ns][ca] = __builtin_amdgcn_mfma_f32_16x16x32_bf16(aH[ca], rLf[ns][kb], acc[ns][ca], 0, 0, 0);
        }
    }
    // C/D layout: col(lane&15) = query row offset; row((lane>>4)*4+r) = candidate offset.
#pragma unroll
    for (int ns = 0; ns < 2; ++ns)
#pragma unroll
      for (int ca = 0; ca < 4; ++ca)
#pragma unroll
        for (int r = 0; r < 4; ++r) {
          float s = acc[ns][ca][r];
          if (s > ls[ns][LTOP - 1]) {
            ls[ns][LTOP - 1] = s; lid[ns][LTOP - 1] = mbase + ca * 16 + kl * 4 + r;
#pragma unroll
            for (int j = LTOP - 1; j > 0; --j) {
              if (ls[ns][j] > ls[ns][j - 1]) {
                float tf = ls[ns][j]; ls[ns][j] = ls[ns][j - 1]; ls[ns][j - 1] = tf;
                int ti = lid[ns][j]; lid[ns][j] = lid[ns][j - 1]; lid[ns][j - 1] = ti;
              }
            }
          }
        }
  }
  // dump per-lane lists: row's candidates live at [row][wave][kl][j]
#pragma unroll
  for (int ns = 0; ns < 2; ++ns) {
    int row = ns * 16 + pr;
#pragma unroll
    for (int j = 0; j < LTOP; ++j) {
      sSc[row][w][kl][j] = ls[ns][j];
      sId[row][w][kl][j] = lid[ns][j];
    }
  }
  __syncthreads();

  // per-row merge: 128 candidates (4 waves x 4 kl x 8), disjoint m-classes -> unique ids
  for (int rr = 0; rr < 8; ++rr) {
    const int row = w * 8 + rr;
    const int n = nbase + row;
    float c0s = sSc[row][lane >> 5][(lane >> 3) & 3][lane & 7];
    int c0i = sId[row][lane >> 5][(lane >> 3) & 3][lane & 7];
    float c1s = sSc[row][2 + (lane >> 5)][(lane >> 3) & 3][lane & 7];
    int c1i = sId[row][2 + (lane >> 5)][(lane >> 3) & 3][lane & 7];
    int mycand = 0;
    for (int sel = 0; sel < TCAND; ++sel) {
      bool f0 = (c0s > c1s) || (c0s == c1s && c0i < c1i);
      float bs = f0 ? c0s : c1s;
      int bi = f0 ? c0i : c1i;
      int bl = lane, bw = f0 ? 0 : 1;
#pragma unroll
      for (int off = 32; off >= 1; off >>= 1) {
        float os = __shfl_down(bs, off);
        int oi = __shfl_down(bi, off);
        int ol = __shfl_down(bl, off);
        int ow = __shfl_down(bw, off);
        if (os > bs || (os == bs && oi < bi)) { bs = os; bi = oi; bl = ol; bw = ow; }
      }
      int wl = __shfl(bl, 0);
      int ww = __shfl(bw, 0);
      int wi = __shfl(bi, 0);
      if (lane == wl) { if (ww == 0) c0s = -3.0e38f; else c1s = -3.0e38f; }
      if (lane == sel) mycand = wi;
    }
    // exact f64 re-rank of the 24 candidates (matches np f64 top_k; ties -> lower index)
    const float* xm = xT + ((size_t)b * NN + mycand) * CC;
    const float* xr = xT + ((size_t)b * NN + n) * CC;
    double dot = 0.0, m2 = 0.0;
#pragma unroll 4
    for (int j = 0; j < 24; ++j) {
      float4 a = *(const float4*)&xm[j * 4];
      float4 q = *(const float4*)&xr[j * 4];
      dot = fma((double)q.x, (double)a.x, dot); m2 = fma((double)a.x, (double)a.x, m2);
      dot = fma((double)q.y, (double)a.y, dot); m2 = fma((double)a.y, (double)a.y, m2);
      dot = fma((double)q.z, (double)a.z, dot); m2 = fma((double)a.z, (double)a.z, m2);
      dot = fma((double)q.w, (double)a.w, dot); m2 = fma((double)a.w, (double)a.w, m2);
    }
    double cur = (lane < TCAND) ? (2.0 * dot - m2) : -1.0e300;
    int curi = (lane < TCAND) ? mycand : 0x7fffffff;
    int* orow = idxout + ((size_t)b * NN + n) * KK;
    for (int sel = 0; sel < KK; ++sel) {
      double ts2 = cur; int ti2 = curi;
#pragma unroll
      for (int off = 32; off >= 1; off >>= 1) {
        double os = __shfl_down(ts2, off);
        int oi = __shfl_down(ti2, off);
        if (os > ts2 || (os == ts2 && oi < ti2)) { ts2 = os; ti2 = oi; }
      }
      int wi = __shfl(ti2, 0);
      if (curi == wi) cur = -1.0e300;
      if (lane == 0) orow[sel] = wi;
    }
  }
}

// ---------------- kernel 3: BN statistics over edge norms ----------------
__global__ __launch_bounds__(256) void k_stats(
    const float* __restrict__ yF1, const float* __restrict__ yFc,
    const int* __restrict__ idx, double* __restrict__ stats) {
  __shared__ float r1[256], r2[256];
  const int t = threadIdx.x, o = t & 31, nl = t >> 5;
  const int b = blockIdx.x >> 9;
  const int n = (blockIdx.x & 511) * 8 + nl;
  const size_t cb = (size_t)(b * NN + n) * CC + o * 3;
  const float pc0 = yFc[cb], pc1 = yFc[cb + 1], pc2 = yFc[cb + 2];
  const int* ip = idx + (size_t)(b * NN + n) * KK;
  float s1 = 0.f, s2 = 0.f;
  for (int k = 0; k < KK; ++k) {
    int m = ip[k];
    size_t a = (size_t)(b * NN + m) * CC + o * 3;
    float p0 = yF1[a] + pc0, p1 = yF1[a + 1] + pc1, p2 = yF1[a + 2] + pc2;
    float nr = sqrtf(p0 * p0 + p1 * p1 + p2 * p2) + 1e-6f;
    s1 += nr; s2 = fmaf(nr, nr, s2);
  }
  r1[t] = s1; r2[t] = s2; __syncthreads();
  if (t < 128) { r1[t] += r1[t + 128]; r2[t] += r2[t + 128]; } __syncthreads();
  if (t < 64) { r1[t] += r1[t + 64]; r2[t] += r2[t + 64]; } __syncthreads();
  if (t < 32) {
    float a1 = r1[t] + r1[t + 32];
    float a2 = r2[t] + r2[t + 32];
    atomicAdd(&stats[t], (double)a1);
    atomicAdd(&stats[32 + t], (double)a2);
  }
}

// ---------------- kernel 4: BN scale/shift ----------------
__global__ void k_bn(const double* __restrict__ stats, const float* __restrict__ gamma,
                     const float* __restrict__ beta, float* __restrict__ ss) {
  int o = threadIdx.x;
  if (o >= 32) return;
  const double M = (double)BB * NN * KK;
  double mean = stats[o] / M;
  double var = stats[32 + o] / M - mean * mean;
  double inv = 1.0 / sqrt(var + 1e-5);
  ss[o] = (float)((double)gamma[o] * inv);
  ss[32 + o] = (float)((double)beta[o] - mean * (double)gamma[o] * inv);
}

// ---------------- kernel 5: gather + activation + mean over k ----------------
__global__ __launch_bounds__(256) void k_out(
    const float* __restrict__ yF1, const float* __restrict__ yFc,
    const float* __restrict__ yD1, const float* __restrict__ yDc,
    const int* __restrict__ idx, const float* __restrict__ ss,
    float* __restrict__ out) {
  const int t = threadIdx.x, o = t & 31, nl = t >> 5;
  const int b = blockIdx.x >> 9;
  const int n = (blockIdx.x & 511) * 8 + nl;
  const size_t cb = (size_t)(b * NN + n) * CC + o * 3;
  const float pc0 = yFc[cb], pc1 = yFc[cb + 1], pc2 = yFc[cb + 2];
  const float dc0 = yDc[cb], dc1 = yDc[cb + 1], dc2 = yDc[cb + 2];
  const float sc = ss[o], sh = ss[32 + o];
  const int* ip = idx + (size_t)(b * NN + n) * KK;
  float a0 = 0.f, a1 = 0.f, a2 = 0.f;
  for (int k = 0; k < KK; ++k) {
    int m = ip[k];
    size_t a = (size_t)(b * NN + m) * CC + o * 3;
    float p0 = yF1[a] + pc0, p1 = yF1[a + 1] + pc1, p2 = yF1[a + 2] + pc2;
    float d0 = yD1[a] + dc0, d1 = yD1[a + 1] + dc1, d2 = yD1[a + 2] + dc2;
    float nr = sqrtf(p0 * p0 + p1 * p1 + p2 * p2) + 1e-6f;
    float f = (sc * nr + sh) / nr;
    p0 *= f; p1 *= f; p2 *= f;
    float dt = p0 * d0 + p1 * d1 + p2 * d2;
    float w8 = (dt >= 0.f) ? 0.f : 0.8f * dt / (d0 * d0 + d1 * d1 + d2 * d2 + 1e-6f);
    a0 += p0 - w8 * d0; a1 += p1 - w8 * d1; a2 += p2 - w8 * d2;
  }
  const float inv = 1.f / (float)KK;
  const size_t ob = ((size_t)(b * OO + o) * 3) * NN + n;
  out[ob] = a0 * inv; out[ob + NN] = a1 * inv; out[ob + 2 * NN] = a2 * inv;
}

extern "C" void kernel_launch(void* const* d_in, const int* in_sizes, int n_in,
                              void* d_out, int out_size, void* d_ws, size_t ws_size,
                              hipStream_t stream) {
  (void)in_sizes; (void)n_in; (void)out_size;
  const float* x = (const float*)d_in[0];
  const float* Wf = (const float*)d_in[1];
  const float* Wd = (const float*)d_in[2];
  const float* gamma = (const float*)d_in[3];
  const float* beta = (const float*)d_in[4];
  float* out = (float*)d_out;

  char* ws = (char*)d_ws;
  size_t off = 0;
  auto alloc = [&](size_t bytes) -> void* {
    void* p = ws + off;
    off += (bytes + 255) & ~(size_t)255;
    return p;
  };
  float* yF1 = (float*)alloc((size_t)PTS * CC * 4);
  float* yFc = (float*)alloc((size_t)PTS * CC * 4);
  float* yD1 = (float*)alloc((size_t)PTS * CC * 4);
  float* yDc = (float*)alloc((size_t)PTS * CC * 4);
  float* xx  = (float*)alloc((size_t)PTS * 4);
  int* idx   = (int*)alloc((size_t)PTS * KK * 4);
  double* stats = (double*)alloc(64 * 8);
  float* ss  = (float*)alloc(64 * 4);
  unsigned short* hl = (unsigned short*)alloc((size_t)PTS * 192 * 2);
  float* xT  = (float*)alloc((size_t)PTS * CC * 4);
  if (ws_size < off) return;

  hipMemsetAsync(stats, 0, 64 * 8, stream);
  k_feat<<<dim3(PTS / 8), dim3(256), 0, stream>>>(x, Wf, Wd, yF1, yFc, yD1, yDc, xx);
  k_prep<<<dim3(PTS / 64), dim3(256), 0, stream>>>(x, hl, xT);
  k_dist<<<dim3(NN / 32, BB), dim3(256), 0, stream>>>(hl, xx, xT, idx);
  k_stats<<<dim3(PTS / 8), dim3(256), 0, stream>>>(yF1, yFc, idx, stats);
  k_bn<<<dim3(1), dim3(64), 0, stream>>>(stats, gamma, beta, ss);
  k_out<<<dim3(PTS / 8), dim3(256), 0, stream>>>(yF1, yFc, yD1, yDc, idx, ss, out);
}

// Round 5
// 463.507 us; speedup vs baseline: 1.1682x; 1.1682x over previous
//
#include <hip/hip_runtime.h>

// Local context aggregation (DGCNN edge-conv style), MI355X.
// Pipeline:
//   k_feat : per-point transforms yF1=A1f·x, yFc=(A2f-A1f)·x, yD1, yDc + xx=|x|^2
//   k_prep : split-bf16 tables hl[n][hi96|lo96] + transposed xT[n][96] f32
//   k_dist : FUSED MFMA score + top-k. Block = 16 query rows x all 4096 candidates,
//            4 waves (1024 cands each). 1024 blocks -> 4 waves/SIMD (R4 was 2: latency-bound).
//            Per-lane top-12 register lists -> LDS dump -> rank-count merge (no serial
//            shfl chains) -> fp32 top-24 -> exact f64 re-rank -> idx[20].
//   k_stats/k_bn/k_out : BN over edge norms + directional leaky act + mean over k
// ws usage: ~39 MB fixed.

namespace {
constexpr int BB = 4;
constexpr int NN = 4096;
constexpr int KK = 20;
constexpr int CC = 96;      // 32 features x 3 dims
constexpr int OO = 32;
constexpr int PTS = BB * NN;
constexpr int LT = 12;      // per-lane top list depth
constexpr int TCAND = 24;   // candidates sent to f64 refine
constexpr int NENT = 4 * 4 * LT;  // entries per row: 4 waves x 4 kl x 12 = 192
constexpr int RSTRIDE = 100;
}

using bf16x8 = __attribute__((ext_vector_type(8))) short;
using f32x4 = __attribute__((ext_vector_type(4))) float;

__device__ __forceinline__ unsigned short f2bf(float f) {
  unsigned u = __float_as_uint(f);
  return (unsigned short)((u + 0x7fff + ((u >> 16) & 1)) >> 16);
}
__device__ __forceinline__ float bf2f(unsigned short b) {
  return __uint_as_float((unsigned)b << 16);
}

// ---------------- kernel 1: per-point transforms + |x|^2 ----------------
__global__ __launch_bounds__(256) void k_feat(
    const float* __restrict__ x, const float* __restrict__ Wf,
    const float* __restrict__ Wd,
    float* __restrict__ yF1, float* __restrict__ yFc,
    float* __restrict__ yD1, float* __restrict__ yDc,
    float* __restrict__ xx) {
  __shared__ float sW[4][32][32];
  __shared__ float sx[8][RSTRIDE];
  const int t = threadIdx.x;
  for (int i = t; i < 2048; i += 256) {
    int o = i & 31, f = (i >> 5) & 31, which = i >> 10;
    const float* W = which ? Wd : Wf;
    float a1 = W[o * 64 + f], a2 = W[o * 64 + 32 + f];
    sW[which * 2 + 0][f][o] = a1;
    sW[which * 2 + 1][f][o] = a2 - a1;
  }
  const int b = blockIdx.x >> 9;
  const int n0 = (blockIdx.x & 511) * 8;
  for (int i = t; i < 8 * CC; i += 256) {
    int pl = i & 7, c = i >> 3;
    sx[pl][c] = x[((size_t)b * CC + c) * NN + n0 + pl];
  }
  __syncthreads();
  const int o = t & 31, pl = t >> 5;
  float aF1[3] = {0.f, 0.f, 0.f}, aFc[3] = {0.f, 0.f, 0.f};
  float aD1[3] = {0.f, 0.f, 0.f}, aDc[3] = {0.f, 0.f, 0.f};
#pragma unroll
  for (int f = 0; f < 32; ++f) {
    float w0 = sW[0][f][o], w1 = sW[1][f][o];
    float w2 = sW[2][f][o], w3 = sW[3][f][o];
#pragma unroll
    for (int dd = 0; dd < 3; ++dd) {
      float v = sx[pl][f * 3 + dd];
      aF1[dd] = fmaf(w0, v, aF1[dd]);
      aFc[dd] = fmaf(w1, v, aFc[dd]);
      aD1[dd] = fmaf(w2, v, aD1[dd]);
      aDc[dd] = fmaf(w3, v, aDc[dd]);
    }
  }
  const size_t pt = (size_t)(b * NN + n0 + pl) * CC + o * 3;
#pragma unroll
  for (int dd = 0; dd < 3; ++dd) {
    yF1[pt + dd] = aF1[dd]; yFc[pt + dd] = aFc[dd];
    yD1[pt + dd] = aD1[dd]; yDc[pt + dd] = aDc[dd];
  }
  float part = 0.f;
#pragma unroll
  for (int dd = 0; dd < 3; ++dd) { float v = sx[pl][o * 3 + dd]; part += v * v; }
#pragma unroll
  for (int off = 16; off >= 1; off >>= 1) part += __shfl_down(part, off, 32);
  if (o == 0) xx[b * NN + n0 + pl] = part;
}

// ---------------- kernel 1b: split-bf16 + transposed tables ----------------
__global__ __launch_bounds__(256) void k_prep(
    const float* __restrict__ x, unsigned short* __restrict__ hl,
    float* __restrict__ xT) {
  __shared__ float tile[CC][65];
  const int t = threadIdx.x;
  const int b = blockIdx.x >> 6;             // 64 blocks per batch
  const int n0 = (blockIdx.x & 63) * 64;
#pragma unroll
  for (int i = 0; i < 24; ++i) {
    int v = i * 256 + t;
    int c = v >> 6, nn = v & 63;
    tile[c][nn] = x[((size_t)b * CC + c) * NN + n0 + nn];
  }
  __syncthreads();
  // hl rows: [hi 96 | lo 96] bf16, written as 24 x 16B chunks per row
#pragma unroll
  for (int i = 0; i < 6; ++i) {
    int v = i * 256 + t;                    // 0..1535 over 64 rows x 24 chunks
    int row = v / 24, k8 = v % 24;
    unsigned hb[4];
    if (k8 < 12) {
      int c0 = k8 * 8;
#pragma unroll
      for (int j = 0; j < 4; ++j) {
        unsigned short l16 = f2bf(tile[c0 + 2 * j][row]);
        unsigned short h16 = f2bf(tile[c0 + 2 * j + 1][row]);
        hb[j] = (unsigned)l16 | ((unsigned)h16 << 16);
      }
    } else {
      int c0 = (k8 - 12) * 8;
#pragma unroll
      for (int j = 0; j < 4; ++j) {
        float f0 = tile[c0 + 2 * j][row], f1 = tile[c0 + 2 * j + 1][row];
        unsigned short h0 = f2bf(f0), h1 = f2bf(f1);
        unsigned short l0 = f2bf(f0 - bf2f(h0)), l1 = f2bf(f1 - bf2f(h1));
        hb[j] = (unsigned)l0 | ((unsigned)l1 << 16);
      }
    }
    *(uint4*)(hl + (size_t)(b * NN + n0 + row) * 192 + k8 * 8) =
        make_uint4(hb[0], hb[1], hb[2], hb[3]);
  }
  // xT rows: 96 f32 contiguous per point
#pragma unroll
  for (int i = 0; i < 6; ++i) {
    int v = i * 256 + t;
    int row = v / 24, q = v % 24;
    float4 o4;
    o4.x = tile[q * 4 + 0][row]; o4.y = tile[q * 4 + 1][row];
    o4.z = tile[q * 4 + 2][row]; o4.w = tile[q * 4 + 3][row];
    *(float4*)(xT + (size_t)(b * NN + n0 + row) * CC + q * 4) = o4;
  }
}

// ---------------- kernel 2: FUSED MFMA score + top-k (high occupancy) ----------------
// Block = 256 thr = 4 waves, 16 query rows (one col-fragment), all 4096 candidates.
// Wave w scans candidates [w*1024, (w+1)*1024). Score = dot - 0.5*xx[m].
// Per-lane (wave,kl)-slot keeps top-12 of its 256-candidate class; rank-count merge.
__global__ __launch_bounds__(256, 4) void k_dist(
    const unsigned short* __restrict__ hl, const float* __restrict__ xx,
    const float* __restrict__ xT, int* __restrict__ idxout) {
  __shared__ float sEnt[16][NENT + 2][2];   // [row][entry][score, id-bits], padded
  __shared__ int sTop[16][TCAND];
  const int t = threadIdx.x, lane = t & 63, w = t >> 6;
  const int b = blockIdx.y;
  const int nbase = blockIdx.x * 16;
  const unsigned short* hb = hl + (size_t)b * NN * 192;
  const float* xxb = xx + b * NN;
  const int kl = lane >> 4, pr = lane & 15;

  // resident operand-B fragments: the block's 16 query rows (col axis)
  bf16x8 rHf[3], rLf[3];
#pragma unroll
  for (int kb = 0; kb < 3; ++kb) {
    const unsigned short* p = hb + (size_t)(nbase + pr) * 192 + (kb * 4 + kl) * 8;
    rHf[kb] = *(const bf16x8*)p;
    rLf[kb] = *(const bf16x8*)(p + 96);
  }

  float ls[LT]; int lid[LT];
#pragma unroll
  for (int j = 0; j < LT; ++j) { ls[j] = -3.0e38f; lid[j] = 0x7fffffff; }

  for (int mt = 0; mt < 16; ++mt) {
    const int mbase = w * 1024 + mt * 64;
    f32x4 acc[4];
#pragma unroll
    for (int ca = 0; ca < 4; ++ca) {
      float4 xv = *(const float4*)&xxb[mbase + ca * 16 + kl * 4];
      acc[ca] = {-0.5f * xv.x, -0.5f * xv.y, -0.5f * xv.z, -0.5f * xv.w};
    }
#pragma unroll
    for (int kb = 0; kb < 3; ++kb) {
      bf16x8 aH[4], aL[4];
#pragma unroll
      for (int ca = 0; ca < 4; ++ca) {
        const unsigned short* p = hb + (size_t)(mbase + ca * 16 + pr) * 192 + (kb * 4 + kl) * 8;
        aH[ca] = *(const bf16x8*)p;
        aL[ca] = *(const bf16x8*)(p + 96);
      }
      // (candH+candL)·(rowH+rowL) ~= cH·rH + cL·rH + cH·rL  (lo·lo ~2^-16)
#pragma unroll
      for (int ca = 0; ca < 4; ++ca) {
        acc[ca] = __builtin_amdgcn_mfma_f32_16x16x32_bf16(aH[ca], rHf[kb], acc[ca], 0, 0, 0);
        acc[ca] = __builtin_amdgcn_mfma_f32_16x16x32_bf16(aL[ca], rHf[kb], acc[ca], 0, 0, 0);
        acc[ca] = __builtin_amdgcn_mfma_f32_16x16x32_bf16(aH[ca], rLf[kb], acc[ca], 0, 0, 0);
      }
    }
    // C/D layout: col(lane&15) = query row; row((lane>>4)*4+r) = candidate offset.
#pragma unroll
    for (int ca = 0; ca < 4; ++ca)
#pragma unroll
      for (int r = 0; r < 4; ++r) {
        float s = acc[ca][r];
        if (s > ls[LT - 1]) {
          ls[LT - 1] = s; lid[LT - 1] = mbase + ca * 16 + kl * 4 + r;
#pragma unroll
          for (int j = LT - 1; j > 0; --j) {
            if (ls[j] > ls[j - 1]) {
              float tf = ls[j]; ls[j] = ls[j - 1]; ls[j - 1] = tf;
              int ti = lid[j]; lid[j] = lid[j - 1]; lid[j - 1] = ti;
            }
          }
        }
      }
  }
  // dump per-lane lists: entry e = w*48 + kl*12 + j for row pr
#pragma unroll
  for (int j = 0; j < LT; ++j) {
    int e = (w * 4 + kl) * LT + j;
    sEnt[pr][e][0] = ls[j];
    sEnt[pr][e][1] = __int_as_float(lid[j]);
  }
  __syncthreads();

  // rank-count merge: wave w handles rows w*4..w*4+3; lane owns entries lane+64c.
  // (wave,kl) classes partition candidates -> ids unique; ties broken by id -> ranks unique.
#pragma unroll
  for (int rr = 0; rr < 4; ++rr) {
    const int row = w * 4 + rr;
    float osr[3]; int oid[3]; int rk[3] = {0, 0, 0};
#pragma unroll
    for (int c = 0; c < 3; ++c) {
      osr[c] = sEnt[row][lane + 64 * c][0];
      oid[c] = __float_as_int(sEnt[row][lane + 64 * c][1]);
    }
    for (int i = 0; i < NENT; ++i) {
      float si = sEnt[row][i][0];
      int ii = __float_as_int(sEnt[row][i][1]);
#pragma unroll
      for (int c = 0; c < 3; ++c)
        rk[c] += (si > osr[c] || (si == osr[c] && ii < oid[c])) ? 1 : 0;
    }
#pragma unroll
    for (int c = 0; c < 3; ++c)
      if (rk[c] < TCAND) sTop[row][rk[c]] = oid[c];
  }
  __syncthreads();

  // exact f64 re-rank of the 24 candidates (matches np f64 top_k; ties -> lower index)
  for (int rr = 0; rr < 4; ++rr) {
    const int row = w * 4 + rr;
    const int n = nbase + row;
    const int mycand = sTop[row][(lane < TCAND) ? lane : (TCAND - 1)];
    const float* xm = xT + ((size_t)b * NN + mycand) * CC;
    const float* xr = xT + ((size_t)b * NN + n) * CC;
    double dot = 0.0, m2 = 0.0;
#pragma unroll 4
    for (int j = 0; j < 24; ++j) {
      float4 a = *(const float4*)&xm[j * 4];
      float4 q = *(const float4*)&xr[j * 4];
      dot = fma((double)q.x, (double)a.x, dot); m2 = fma((double)a.x, (double)a.x, m2);
      dot = fma((double)q.y, (double)a.y, dot); m2 = fma((double)a.y, (double)a.y, m2);
      dot = fma((double)q.z, (double)a.z, dot); m2 = fma((double)a.z, (double)a.z, m2);
      dot = fma((double)q.w, (double)a.w, dot); m2 = fma((double)a.w, (double)a.w, m2);
    }
    double cur = (lane < TCAND) ? (2.0 * dot - m2) : -1.0e300;
    int curi = (lane < TCAND) ? mycand : 0x7fffffff;
    int* orow = idxout + ((size_t)b * NN + n) * KK;
    for (int sel = 0; sel < KK; ++sel) {
      double ts2 = cur; int ti2 = curi;
#pragma unroll
      for (int off = 32; off >= 1; off >>= 1) {
        double os = __shfl_down(ts2, off);
        int oi = __shfl_down(ti2, off);
        if (os > ts2 || (os == ts2 && oi < ti2)) { ts2 = os; ti2 = oi; }
      }
      int wi = __shfl(ti2, 0);
      if (curi == wi) cur = -1.0e300;
      if (lane == 0) orow[sel] = wi;
    }
  }
}

// ---------------- kernel 3: BN statistics over edge norms ----------------
__global__ __launch_bounds__(256) void k_stats(
    const float* __restrict__ yF1, const float* __restrict__ yFc,
    const int* __restrict__ idx, double* __restrict__ stats) {
  __shared__ float r1[256], r2[256];
  const int t = threadIdx.x, o = t & 31, nl = t >> 5;
  const int b = blockIdx.x >> 9;
  const int n = (blockIdx.x & 511) * 8 + nl;
  const size_t cb = (size_t)(b * NN + n) * CC + o * 3;
  const float pc0 = yFc[cb], pc1 = yFc[cb + 1], pc2 = yFc[cb + 2];
  const int* ip = idx + (size_t)(b * NN + n) * KK;
  float s1 = 0.f, s2 = 0.f;
  for (int k = 0; k < KK; ++k) {
    int m = ip[k];
    size_t a = (size_t)(b * NN + m) * CC + o * 3;
    float p0 = yF1[a] + pc0, p1 = yF1[a + 1] + pc1, p2 = yF1[a + 2] + pc2;
    float nr = sqrtf(p0 * p0 + p1 * p1 + p2 * p2) + 1e-6f;
    s1 += nr; s2 = fmaf(nr, nr, s2);
  }
  r1[t] = s1; r2[t] = s2; __syncthreads();
  if (t < 128) { r1[t] += r1[t + 128]; r2[t] += r2[t + 128]; } __syncthreads();
  if (t < 64) { r1[t] += r1[t + 64]; r2[t] += r2[t + 64]; } __syncthreads();
  if (t < 32) {
    float a1 = r1[t] + r1[t + 32];
    float a2 = r2[t] + r2[t + 32];
    atomicAdd(&stats[t], (double)a1);
    atomicAdd(&stats[32 + t], (double)a2);
  }
}

// ---------------- kernel 4: BN scale/shift ----------------
__global__ void k_bn(const double* __restrict__ stats, const float* __restrict__ gamma,
                     const float* __restrict__ beta, float* __restrict__ ss) {
  int o = threadIdx.x;
  if (o >= 32) return;
  const double M = (double)BB * NN * KK;
  double mean = stats[o] / M;
  double var = stats[32 + o] / M - mean * mean;
  double inv = 1.0 / sqrt(var + 1e-5);
  ss[o] = (float)((double)gamma[o] * inv);
  ss[32 + o] = (float)((double)beta[o] - mean * (double)gamma[o] * inv);
}

// ---------------- kernel 5: gather + activation + mean over k ----------------
__global__ __launch_bounds__(256) void k_out(
    const float* __restrict__ yF1, const float* __restrict__ yFc,
    const float* __restrict__ yD1, const float* __restrict__ yDc,
    const int* __restrict__ idx, const float* __restrict__ ss,
    float* __restrict__ out) {
  const int t = threadIdx.x, o = t & 31, nl = t >> 5;
  const int b = blockIdx.x >> 9;
  const int n = (blockIdx.x & 511) * 8 + nl;
  const size_t cb = (size_t)(b * NN + n) * CC + o * 3;
  const float pc0 = yFc[cb], pc1 = yFc[cb + 1], pc2 = yFc[cb + 2];
  const float dc0 = yDc[cb], dc1 = yDc[cb + 1], dc2 = yDc[cb + 2];
  const float sc = ss[o], sh = ss[32 + o];
  const int* ip = idx + (size_t)(b * NN + n) * KK;
  float a0 = 0.f, a1 = 0.f, a2 = 0.f;
  for (int k = 0; k < KK; ++k) {
    int m = ip[k];
    size_t a = (size_t)(b * NN + m) * CC + o * 3;
    float p0 = yF1[a] + pc0, p1 = yF1[a + 1] + pc1, p2 = yF1[a + 2] + pc2;
    float d0 = yD1[a] + dc0, d1 = yD1[a + 1] + dc1, d2 = yD1[a + 2] + dc2;
    float nr = sqrtf(p0 * p0 + p1 * p1 + p2 * p2) + 1e-6f;
    float f = (sc * nr + sh) / nr;
    p0 *= f; p1 *= f; p2 *= f;
    float dt = p0 * d0 + p1 * d1 + p2 * d2;
    float w8 = (dt >= 0.f) ? 0.f : 0.8f * dt / (d0 * d0 + d1 * d1 + d2 * d2 + 1e-6f);
    a0 += p0 - w8 * d0; a1 += p1 - w8 * d1; a2 += p2 - w8 * d2;
  }
  const float inv = 1.f / (float)KK;
  const size_t ob = ((size_t)(b * OO + o) * 3) * NN + n;
  out[ob] = a0 * inv; out[ob + NN] = a1 * inv; out[ob + 2 * NN] = a2 * inv;
}

extern "C" void kernel_launch(void* const* d_in, const int* in_sizes, int n_in,
                              void* d_out, int out_size, void* d_ws, size_t ws_size,
                              hipStream_t stream) {
  (void)in_sizes; (void)n_in; (void)out_size;
  const float* x = (const float*)d_in[0];
  const float* Wf = (const float*)d_in[1];
  const float* Wd = (const float*)d_in[2];
  const float* gamma = (const float*)d_in[3];
  const float* beta = (const float*)d_in[4];
  float* out = (float*)d_out;

  char* ws = (char*)d_ws;
  size_t off = 0;
  auto alloc = [&](size_t bytes) -> void* {
    void* p = ws + off;
    off += (bytes + 255) & ~(size_t)255;
    return p;
  };
  float* yF1 = (float*)alloc((size_t)PTS * CC * 4);
  float* yFc = (float*)alloc((size_t)PTS * CC * 4);
  float* yD1 = (float*)alloc((size_t)PTS * CC * 4);
  float* yDc = (float*)alloc((size_t)PTS * CC * 4);
  float* xx  = (float*)alloc((size_t)PTS * 4);
  int* idx   = (int*)alloc((size_t)PTS * KK * 4);
  double* stats = (double*)alloc(64 * 8);
  float* ss  = (float*)alloc(64 * 4);
  unsigned short* hl = (unsigned short*)alloc((size_t)PTS * 192 * 2);
  float* xT  = (float*)alloc((size_t)PTS * CC * 4);
  if (ws_size < off) return;

  hipMemsetAsync(stats, 0, 64 * 8, stream);
  k_feat<<<dim3(PTS / 8), dim3(256), 0, stream>>>(x, Wf, Wd, yF1, yFc, yD1, yDc, xx);
  k_prep<<<dim3(PTS / 64), dim3(256), 0, stream>>>(x, hl, xT);
  k_dist<<<dim3(NN / 16, BB), dim3(256), 0, stream>>>(hl, xx, xT, idx);
  k_stats<<<dim3(PTS / 8), dim3(256), 0, stream>>>(yF1, yFc, idx, stats);
  k_bn<<<dim3(1), dim3(64), 0, stream>>>(stats, gamma, beta, ss);
  k_out<<<dim3(PTS / 8), dim3(256), 0, stream>>>(yF1, yFc, yD1, yDc, idx, ss, out);
}

// Round 6
// 347.359 us; speedup vs baseline: 1.5588x; 1.3344x over previous
//
#include <hip/hip_runtime.h>

// Local context aggregation (DGCNN edge-conv style), MI355X.
// Pipeline:
//   k_feat : per-point transforms yF1=A1f·x, yFc=(A2f-A1f)·x, yD1, yDc + xx=|x|^2
//   k_prep : split-bf16 tables hl[n][hi96|lo96] + transposed xT[n][96] f32
//   k_dist : FUSED MFMA score + top-k. Block = 16 query rows x all 4096 candidates.
//            Batch-per-XCD block swizzle (one 1.6MB table per XCD L2). Selection via
//            packed-u32 keys (score hi-bits | unique class/local tag) maintained with a
//            branchless v_min/v_max cascade; rank-count merge; exact-f64 re-rank with
//            packed-u64 keys -> idx[20]. Scores never touch HBM.
//   k_stats/k_bn/k_out : BN over edge norms + directional leaky act + mean over k
// ws usage: ~39 MB fixed.

namespace {
constexpr int BB = 4;
constexpr int NN = 4096;
constexpr int KK = 20;
constexpr int CC = 96;      // 32 features x 3 dims
constexpr int OO = 32;
constexpr int PTS = BB * NN;
constexpr int LT = 12;      // per-(wave,kl)-class top list depth (class = 256 cands)
constexpr int TCAND = 24;   // candidates sent to f64 refine
constexpr int NENT = 16 * LT;     // entries per row: 4 waves x 4 kl x 12 = 192
constexpr int NENT_PAD = 196;     // padded row stride (words): 196%32=4 -> banks spread
constexpr int RSTRIDE = 100;
}

using bf16x8 = __attribute__((ext_vector_type(8))) short;
using f32x4 = __attribute__((ext_vector_type(4))) float;

__device__ __forceinline__ unsigned short f2bf(float f) {
  unsigned u = __float_as_uint(f);
  return (unsigned short)((u + 0x7fff + ((u >> 16) & 1)) >> 16);
}
__device__ __forceinline__ float bf2f(unsigned short b) {
  return __uint_as_float((unsigned)b << 16);
}

// ---------------- kernel 1: per-point transforms + |x|^2 ----------------
__global__ __launch_bounds__(256) void k_feat(
    const float* __restrict__ x, const float* __restrict__ Wf,
    const float* __restrict__ Wd,
    float* __restrict__ yF1, float* __restrict__ yFc,
    float* __restrict__ yD1, float* __restrict__ yDc,
    float* __restrict__ xx) {
  __shared__ float sW[4][32][32];
  __shared__ float sx[8][RSTRIDE];
  const int t = threadIdx.x;
  for (int i = t; i < 2048; i += 256) {
    int o = i & 31, f = (i >> 5) & 31, which = i >> 10;
    const float* W = which ? Wd : Wf;
    float a1 = W[o * 64 + f], a2 = W[o * 64 + 32 + f];
    sW[which * 2 + 0][f][o] = a1;
    sW[which * 2 + 1][f][o] = a2 - a1;
  }
  const int b = blockIdx.x >> 9;
  const int n0 = (blockIdx.x & 511) * 8;
  for (int i = t; i < 8 * CC; i += 256) {
    int pl = i & 7, c = i >> 3;
    sx[pl][c] = x[((size_t)b * CC + c) * NN + n0 + pl];
  }
  __syncthreads();
  const int o = t & 31, pl = t >> 5;
  float aF1[3] = {0.f, 0.f, 0.f}, aFc[3] = {0.f, 0.f, 0.f};
  float aD1[3] = {0.f, 0.f, 0.f}, aDc[3] = {0.f, 0.f, 0.f};
#pragma unroll
  for (int f = 0; f < 32; ++f) {
    float w0 = sW[0][f][o], w1 = sW[1][f][o];
    float w2 = sW[2][f][o], w3 = sW[3][f][o];
#pragma unroll
    for (int dd = 0; dd < 3; ++dd) {
      float v = sx[pl][f * 3 + dd];
      aF1[dd] = fmaf(w0, v, aF1[dd]);
      aFc[dd] = fmaf(w1, v, aFc[dd]);
      aD1[dd] = fmaf(w2, v, aD1[dd]);
      aDc[dd] = fmaf(w3, v, aDc[dd]);
    }
  }
  const size_t pt = (size_t)(b * NN + n0 + pl) * CC + o * 3;
#pragma unroll
  for (int dd = 0; dd < 3; ++dd) {
    yF1[pt + dd] = aF1[dd]; yFc[pt + dd] = aFc[dd];
    yD1[pt + dd] = aD1[dd]; yDc[pt + dd] = aDc[dd];
  }
  float part = 0.f;
#pragma unroll
  for (int dd = 0; dd < 3; ++dd) { float v = sx[pl][o * 3 + dd]; part += v * v; }
#pragma unroll
  for (int off = 16; off >= 1; off >>= 1) part += __shfl_down(part, off, 32);
  if (o == 0) xx[b * NN + n0 + pl] = part;
}

// ---------------- kernel 1b: split-bf16 + transposed tables ----------------
__global__ __launch_bounds__(256) void k_prep(
    const float* __restrict__ x, unsigned short* __restrict__ hl,
    float* __restrict__ xT) {
  __shared__ float tile[CC][65];
  const int t = threadIdx.x;
  const int b = blockIdx.x >> 6;             // 64 blocks per batch
  const int n0 = (blockIdx.x & 63) * 64;
#pragma unroll
  for (int i = 0; i < 24; ++i) {
    int v = i * 256 + t;
    int c = v >> 6, nn = v & 63;
    tile[c][nn] = x[((size_t)b * CC + c) * NN + n0 + nn];
  }
  __syncthreads();
  // hl rows: [hi 96 | lo 96] bf16, written as 24 x 16B chunks per row
#pragma unroll
  for (int i = 0; i < 6; ++i) {
    int v = i * 256 + t;                    // 0..1535 over 64 rows x 24 chunks
    int row = v / 24, k8 = v % 24;
    unsigned hb[4];
    if (k8 < 12) {
      int c0 = k8 * 8;
#pragma unroll
      for (int j = 0; j < 4; ++j) {
        unsigned short l16 = f2bf(tile[c0 + 2 * j][row]);
        unsigned short h16 = f2bf(tile[c0 + 2 * j + 1][row]);
        hb[j] = (unsigned)l16 | ((unsigned)h16 << 16);
      }
    } else {
      int c0 = (k8 - 12) * 8;
#pragma unroll
      for (int j = 0; j < 4; ++j) {
        float f0 = tile[c0 + 2 * j][row], f1 = tile[c0 + 2 * j + 1][row];
        unsigned short h0 = f2bf(f0), h1 = f2bf(f1);
        unsigned short l0 = f2bf(f0 - bf2f(h0)), l1 = f2bf(f1 - bf2f(h1));
        hb[j] = (unsigned)l0 | ((unsigned)l1 << 16);
      }
    }
    *(uint4*)(hl + (size_t)(b * NN + n0 + row) * 192 + k8 * 8) =
        make_uint4(hb[0], hb[1], hb[2], hb[3]);
  }
  // xT rows: 96 f32 contiguous per point
#pragma unroll
  for (int i = 0; i < 6; ++i) {
    int v = i * 256 + t;
    int row = v / 24, q = v % 24;
    float4 o4;
    o4.x = tile[q * 4 + 0][row]; o4.y = tile[q * 4 + 1][row];
    o4.z = tile[q * 4 + 2][row]; o4.w = tile[q * 4 + 3][row];
    *(float4*)(xT + (size_t)(b * NN + n0 + row) * CC + q * 4) = o4;
  }
}

// ---------------- kernel 2: FUSED MFMA score + top-k (packed keys) ----------------
// 1-D grid of 1024. Batch-per-XCD swizzle: xcd=wg&7, b=xcd&3 -> each XCD L2 caches one
// per-batch table. Block = 4 waves x 16 query rows; wave w scans candidates
// [w*1024,(w+1)*1024). Score = dot - 0.5*xx[m]; candidate id encoded in key low bits.
__global__ __launch_bounds__(256, 4) void k_dist(
    const unsigned short* __restrict__ hl, const float* __restrict__ xx,
    const float* __restrict__ xT, int* __restrict__ idxout) {
  __shared__ unsigned sEnt[16][NENT_PAD];
  __shared__ int sTop[16][TCAND];
  const int t = threadIdx.x, lane = t & 63, w = t >> 6;
  const int wg = blockIdx.x;
  const int xcd = wg & 7;
  const int b = xcd & 3;
  const int nbase = (((wg >> 3) << 1) | (xcd >> 2)) << 4;   // 0..4080, step 16
  const unsigned short* hb = hl + (size_t)b * NN * 192;
  const float* xxb = xx + b * NN;
  const int kl = lane >> 4, pr = lane & 15;
  const unsigned clsbase = (unsigned)((w * 4 + kl) << 8);

  // resident operand-B fragments: the block's 16 query rows (col axis)
  bf16x8 rHf[3], rLf[3];
#pragma unroll
  for (int kb = 0; kb < 3; ++kb) {
    const unsigned short* p = hb + (size_t)(nbase + pr) * 192 + (kb * 4 + kl) * 8;
    rHf[kb] = *(const bf16x8*)p;
    rLf[kb] = *(const bf16x8*)(p + 96);
  }

  unsigned ls[LT];
#pragma unroll
  for (int j = 0; j < LT; ++j) ls[j] = 0u;   // 0 == -inf key

  for (int mt = 0; mt < 16; ++mt) {
    const int mbase = w * 1024 + mt * 64;
    const unsigned kb255 = clsbase | (unsigned)(255 - mt * 16);
    f32x4 acc[4];
#pragma unroll
    for (int ca = 0; ca < 4; ++ca) {
      float4 xv = *(const float4*)&xxb[mbase + ca * 16 + kl * 4];
      acc[ca] = {-0.5f * xv.x, -0.5f * xv.y, -0.5f * xv.z, -0.5f * xv.w};
    }
#pragma unroll
    for (int kb = 0; kb < 3; ++kb) {
      bf16x8 aH[4], aL[4];
#pragma unroll
      for (int ca = 0; ca < 4; ++ca) {
        const unsigned short* p = hb + (size_t)(mbase + ca * 16 + pr) * 192 + (kb * 4 + kl) * 8;
        aH[ca] = *(const bf16x8*)p;
        aL[ca] = *(const bf16x8*)(p + 96);
      }
      // (candH+candL)·(rowH+rowL) ~= cH·rH + cL·rH + cH·rL  (lo·lo ~2^-16)
#pragma unroll
      for (int ca = 0; ca < 4; ++ca) {
        acc[ca] = __builtin_amdgcn_mfma_f32_16x16x32_bf16(aH[ca], rHf[kb], acc[ca], 0, 0, 0);
        acc[ca] = __builtin_amdgcn_mfma_f32_16x16x32_bf16(aL[ca], rHf[kb], acc[ca], 0, 0, 0);
        acc[ca] = __builtin_amdgcn_mfma_f32_16x16x32_bf16(aH[ca], rLf[kb], acc[ca], 0, 0, 0);
      }
    }
    // C/D layout: col(lane&15) = query row; row((lane>>4)*4+r) = candidate offset.
    // key = monotone(score)[31:12] | class[11:8] | (255-local)[7:0]  (globally unique)
#pragma unroll
    for (int ca = 0; ca < 4; ++ca)
#pragma unroll
      for (int r = 0; r < 4; ++r) {
        unsigned sb = __float_as_uint(acc[ca][r]);
        sb ^= ((unsigned)((int)sb >> 31)) | 0x80000000u;
        unsigned key = (sb & 0xFFFFF000u) | (kb255 - (unsigned)(ca * 4 + r));
        // branchless sorted-desc insert: 2 insts/stage (v_max_u32/v_min_u32)
#pragma unroll
        for (int j = 0; j < LT; ++j) {
          unsigned lo = ls[j] < key ? ls[j] : key;
          ls[j] = ls[j] < key ? key : ls[j];
          key = lo;
        }
      }
  }
  // dump per-lane sorted key lists: row pr, entries [(w*4+kl)*12 .. +12)
  {
    unsigned* dst = &sEnt[pr][(w * 4 + kl) * LT];
    *(uint4*)(dst + 0) = make_uint4(ls[0], ls[1], ls[2], ls[3]);
    *(uint4*)(dst + 4) = make_uint4(ls[4], ls[5], ls[6], ls[7]);
    *(uint4*)(dst + 8) = make_uint4(ls[8], ls[9], ls[10], ls[11]);
  }
  __syncthreads();

  // rank-count merge: wave w handles rows w*4..w*4+3; lane owns entries {lane+64c}.
  // Keys are globally unique -> ranks 0..191 are a permutation -> sTop fully written.
#pragma unroll
  for (int rr = 0; rr < 4; ++rr) {
    const int row = w * 4 + rr;
    unsigned mine[3]; int rk[3] = {0, 0, 0};
#pragma unroll
    for (int c = 0; c < 3; ++c) mine[c] = sEnt[row][lane + 64 * c];
    for (int i4 = 0; i4 < NENT / 4; ++i4) {
      uint4 e = *(const uint4*)&sEnt[row][i4 * 4];
#pragma unroll
      for (int c = 0; c < 3; ++c) {
        rk[c] += (e.x > mine[c]) ? 1 : 0;
        rk[c] += (e.y > mine[c]) ? 1 : 0;
        rk[c] += (e.z > mine[c]) ? 1 : 0;
        rk[c] += (e.w > mine[c]) ? 1 : 0;
      }
    }
#pragma unroll
    for (int c = 0; c < 3; ++c) {
      if (rk[c] < TCAND) {
        unsigned low = mine[c] & 0xFFFu;
        int cls = (int)(low >> 8);
        int loc = 255 - (int)(low & 255u);
        int id = (cls >> 2) * 1024 + (loc >> 4) * 64 + ((loc >> 2) & 3) * 16 +
                 (cls & 3) * 4 + (loc & 3);
        sTop[row][rk[c]] = id;
      }
    }
  }
  __syncthreads();

  // exact f64 re-rank of 24 candidates; 48 lanes (2 per candidate, 48 dims each).
  // u64 key: monotone(f64 score) with low 12 bits = ~cand  (np tie-break: lower id first)
  for (int rr = 0; rr < 4; ++rr) {
    const int row = w * 4 + rr;
    const int n = nbase + row;
    const int ci = (lane < 48) ? (lane >> 1) : 23;
    const int half = lane & 1;
    const int mycand = sTop[row][ci];
    const float* xm = xT + ((size_t)b * NN + mycand) * CC + half * 48;
    const float* xr = xT + ((size_t)b * NN + n) * CC + half * 48;
    double dot = 0.0, m2 = 0.0;
#pragma unroll 4
    for (int j = 0; j < 12; ++j) {
      float4 a = *(const float4*)&xm[j * 4];
      float4 q = *(const float4*)&xr[j * 4];
      dot = fma((double)q.x, (double)a.x, dot); m2 = fma((double)a.x, (double)a.x, m2);
      dot = fma((double)q.y, (double)a.y, dot); m2 = fma((double)a.y, (double)a.y, m2);
      dot = fma((double)q.z, (double)a.z, dot); m2 = fma((double)a.z, (double)a.z, m2);
      dot = fma((double)q.w, (double)a.w, dot); m2 = fma((double)a.w, (double)a.w, m2);
    }
    dot += __shfl_xor(dot, 1);
    m2 += __shfl_xor(m2, 1);
    double sc = 2.0 * dot - m2;
    unsigned long long bits = (unsigned long long)__double_as_longlong(sc);
    bits ^= ((unsigned long long)((long long)bits >> 63)) | 0x8000000000000000ull;
    unsigned long long key = (bits & ~0xFFFull) | (unsigned long long)(4095 - mycand);
    int rank = 0;
#pragma unroll
    for (int j = 0; j < TCAND; ++j) {
      unsigned long long kj = __shfl(key, j * 2);
      rank += (kj > key) ? 1 : 0;
    }
    if (lane < 48 && half == 0 && rank < KK)
      idxout[((size_t)b * NN + n) * KK + rank] = mycand;
  }
}

// ---------------- kernel 3: BN statistics over edge norms ----------------
__global__ __launch_bounds__(256) void k_stats(
    const float* __restrict__ yF1, const float* __restrict__ yFc,
    const int* __restrict__ idx, double* __restrict__ stats) {
  __shared__ float r1[256], r2[256];
  const int t = threadIdx.x, o = t & 31, nl = t >> 5;
  const int b = blockIdx.x >> 9;
  const int n = (blockIdx.x & 511) * 8 + nl;
  const size_t cb = (size_t)(b * NN + n) * CC + o * 3;
  const float pc0 = yFc[cb], pc1 = yFc[cb + 1], pc2 = yFc[cb + 2];
  const int* ip = idx + (size_t)(b * NN + n) * KK;
  float s1 = 0.f, s2 = 0.f;
  for (int k = 0; k < KK; ++k) {
    int m = ip[k];
    size_t a = (size_t)(b * NN + m) * CC + o * 3;
    float p0 = yF1[a] + pc0, p1 = yF1[a + 1] + pc1, p2 = yF1[a + 2] + pc2;
    float nr = sqrtf(p0 * p0 + p1 * p1 + p2 * p2) + 1e-6f;
    s1 += nr; s2 = fmaf(nr, nr, s2);
  }
  r1[t] = s1; r2[t] = s2; __syncthreads();
  if (t < 128) { r1[t] += r1[t + 128]; r2[t] += r2[t + 128]; } __syncthreads();
  if (t < 64) { r1[t] += r1[t + 64]; r2[t] += r2[t + 64]; } __syncthreads();
  if (t < 32) {
    float a1 = r1[t] + r1[t + 32];
    float a2 = r2[t] + r2[t + 32];
    atomicAdd(&stats[t], (double)a1);
    atomicAdd(&stats[32 + t], (double)a2);
  }
}

// ---------------- kernel 4: BN scale/shift ----------------
__global__ void k_bn(const double* __restrict__ stats, const float* __restrict__ gamma,
                     const float* __restrict__ beta, float* __restrict__ ss) {
  int o = threadIdx.x;
  if (o >= 32) return;
  const double M = (double)BB * NN * KK;
  double mean = stats[o] / M;
  double var = stats[32 + o] / M - mean * mean;
  double inv = 1.0 / sqrt(var + 1e-5);
  ss[o] = (float)((double)gamma[o] * inv);
  ss[32 + o] = (float)((double)beta[o] - mean * (double)gamma[o] * inv);
}

// ---------------- kernel 5: gather + activation + mean over k ----------------
__global__ __launch_bounds__(256) void k_out(
    const float* __restrict__ yF1, const float* __restrict__ yFc,
    const float* __restrict__ yD1, const float* __restrict__ yDc,
    const int* __restrict__ idx, const float* __restrict__ ss,
    float* __restrict__ out) {
  const int t = threadIdx.x, o = t & 31, nl = t >> 5;
  const int b = blockIdx.x >> 9;
  const int n = (blockIdx.x & 511) * 8 + nl;
  const size_t cb = (size_t)(b * NN + n) * CC + o * 3;
  const float pc0 = yFc[cb], pc1 = yFc[cb + 1], pc2 = yFc[cb + 2];
  const float dc0 = yDc[cb], dc1 = yDc[cb + 1], dc2 = yDc[cb + 2];
  const float sc = ss[o], sh = ss[32 + o];
  const int* ip = idx + (size_t)(b * NN + n) * KK;
  float a0 = 0.f, a1 = 0.f, a2 = 0.f;
  for (int k = 0; k < KK; ++k) {
    int m = ip[k];
    size_t a = (size_t)(b * NN + m) * CC + o * 3;
    float p0 = yF1[a] + pc0, p1 = yF1[a + 1] + pc1, p2 = yF1[a + 2] + pc2;
    float d0 = yD1[a] + dc0, d1 = yD1[a + 1] + dc1, d2 = yD1[a + 2] + dc2;
    float nr = sqrtf(p0 * p0 + p1 * p1 + p2 * p2) + 1e-6f;
    float f = (sc * nr + sh) / nr;
    p0 *= f; p1 *= f; p2 *= f;
    float dt = p0 * d0 + p1 * d1 + p2 * d2;
    float w8 = (dt >= 0.f) ? 0.f : 0.8f * dt / (d0 * d0 + d1 * d1 + d2 * d2 + 1e-6f);
    a0 += p0 - w8 * d0; a1 += p1 - w8 * d1; a2 += p2 - w8 * d2;
  }
  const float inv = 1.f / (float)KK;
  const size_t ob = ((size_t)(b * OO + o) * 3) * NN + n;
  out[ob] = a0 * inv; out[ob + NN] = a1 * inv; out[ob + 2 * NN] = a2 * inv;
}

extern "C" void kernel_launch(void* const* d_in, const int* in_sizes, int n_in,
                              void* d_out, int out_size, void* d_ws, size_t ws_size,
                              hipStream_t stream) {
  (void)in_sizes; (void)n_in; (void)out_size;
  const float* x = (const float*)d_in[0];
  const float* Wf = (const float*)d_in[1];
  const float* Wd = (const float*)d_in[2];
  const float* gamma = (const float*)d_in[3];
  const float* beta = (const float*)d_in[4];
  float* out = (float*)d_out;

  char* ws = (char*)d_ws;
  size_t off = 0;
  auto alloc = [&](size_t bytes) -> void* {
    void* p = ws + off;
    off += (bytes + 255) & ~(size_t)255;
    return p;
  };
  float* yF1 = (float*)alloc((size_t)PTS * CC * 4);
  float* yFc = (float*)alloc((size_t)PTS * CC * 4);
  float* yD1 = (float*)alloc((size_t)PTS * CC * 4);
  float* yDc = (float*)alloc((size_t)PTS * CC * 4);
  float* xx  = (float*)alloc((size_t)PTS * 4);
  int* idx   = (int*)alloc((size_t)PTS * KK * 4);
  double* stats = (double*)alloc(64 * 8);
  float* ss  = (float*)alloc(64 * 4);
  unsigned short* hl = (unsigned short*)alloc((size_t)PTS * 192 * 2);
  float* xT  = (float*)alloc((size_t)PTS * CC * 4);
  if (ws_size < off) return;

  hipMemsetAsync(stats, 0, 64 * 8, stream);
  k_feat<<<dim3(PTS / 8), dim3(256), 0, stream>>>(x, Wf, Wd, yF1, yFc, yD1, yDc, xx);
  k_prep<<<dim3(PTS / 64), dim3(256), 0, stream>>>(x, hl, xT);
  k_dist<<<dim3(BB * NN / 16), dim3(256), 0, stream>>>(hl, xx, xT, idx);
  k_stats<<<dim3(PTS / 8), dim3(256), 0, stream>>>(yF1, yFc, idx, stats);
  k_bn<<<dim3(1), dim3(64), 0, stream>>>(stats, gamma, beta, ss);
  k_out<<<dim3(PTS / 8), dim3(256), 0, stream>>>(yF1, yFc, yD1, yDc, idx, ss, out);
}